// Round 1
// baseline (354.967 us; speedup 1.0000x reference)
//
#include <hip/hip_runtime.h>

#define N_NODES 20000
#define N_EDGES 200000
#define HID 128

typedef unsigned short u16;
using bf16x8 = __attribute__((ext_vector_type(8))) __bf16;
using f32x4  = __attribute__((ext_vector_type(4))) float;

__device__ __forceinline__ u16 f2bf(float f) {
  union { float f; unsigned u; } v; v.f = f;
  unsigned u = v.u;
  return (u16)((u + 0x7FFFu + ((u >> 16) & 1u)) >> 16);
}
__device__ __forceinline__ float bf2f(unsigned s) {
  union { unsigned u; float f; } v; v.u = s << 16;
  return v.f;
}

__device__ __forceinline__ void zero_acc(f32x4 acc[4][2]) {
#pragma unroll
  for (int i = 0; i < 4; ++i) {
    acc[i][0] = (f32x4){0.f, 0.f, 0.f, 0.f};
    acc[i][1] = (f32x4){0.f, 0.f, 0.f, 0.f};
  }
}

// GEMM: D[64 edges][128 ch] += A(lds)[64][K] * B(packed)[K][128]
// wave w owns n-tiles {2w, 2w+1}; A-frag: A[m=lane&15][k=q*8+j]; B packed so
// lane reads 16B at ((ks*8+ntile)*64+lane)*8 u16.
template <int KSTEPS, int ASTR>
__device__ __forceinline__ void mfma_block(const u16* A, const u16* __restrict__ PB,
                                           int lane, int wave, f32x4 acc[4][2]) {
  const int m = lane & 15, q = lane >> 4;
  const u16* arow0 = A + m * ASTR + q * 8;
  const u16* pb = PB + (wave * 2 * 64 + lane) * 8;
#pragma unroll
  for (int ks = 0; ks < KSTEPS; ++ks) {
    bf16x8 b0 = *(const bf16x8*)(pb + ks * 4096);
    bf16x8 b1 = *(const bf16x8*)(pb + ks * 4096 + 512);
#pragma unroll
    for (int mt = 0; mt < 4; ++mt) {
      bf16x8 a = *(const bf16x8*)(arow0 + mt * 16 * ASTR + ks * 32);
      acc[mt][0] = __builtin_amdgcn_mfma_f32_16x16x32_bf16(a, b0, acc[mt][0], 0, 0, 0);
      acc[mt][1] = __builtin_amdgcn_mfma_f32_16x16x32_bf16(a, b1, acc[mt][1], 0, 0, 0);
    }
  }
}

// C/D layout: row = (lane>>4)*4 + r, col = lane&15 (per 16x16 tile)
template <bool RELU>
__device__ __forceinline__ void store_lds(u16* outbase, int stride, const f32x4 acc[4][2],
                                          int lane, int wave, float bias0, float bias1) {
  const int c = lane & 15, q = lane >> 4;
#pragma unroll
  for (int mt = 0; mt < 4; ++mt)
#pragma unroll
    for (int nt = 0; nt < 2; ++nt) {
      const float bb = nt ? bias1 : bias0;
      const int col = wave * 32 + nt * 16 + c;
#pragma unroll
      for (int r = 0; r < 4; ++r) {
        float v = acc[mt][nt][r] + bb;
        if (RELU) v = fmaxf(v, 0.0f);
        outbase[(mt * 16 + q * 4 + r) * stride + col] = f2bf(v);
      }
    }
}

// ---- fold encoder (conv1d+mean) and fuse into M[128x20], C0[128], Wnt[128] ----
__global__ void k_fold(const float* __restrict__ emb, const float* __restrict__ conv_w,
                       const float* __restrict__ conv_b, const float* __restrict__ fuse_w,
                       const float* __restrict__ fuse_b, float* __restrict__ Mt,
                       float* __restrict__ C0, float* __restrict__ Wnt) {
  __shared__ float Ash[128][21];
  int o = threadIdx.x;  // 128 threads
  {
    float b0 = conv_b[o];
#pragma unroll
    for (int p = 0; p < 5; ++p) {
#pragma unroll
      for (int i = 0; i < 8; ++i) {
        float s = 0.f;
#pragma unroll
        for (int k = 0; k < 3; ++k) {
          int t = p + 1 - k;
          if (t >= 0 && t < 5) s += conv_w[(o * 8 + i) * 3 + k];
        }
        s *= 0.2f;
        if (i < 4) Ash[o][p * 4 + i] = s;
        else b0 += emb[p * 4 + (i - 4)] * s;
      }
    }
    Ash[o][20] = b0;
  }
  __syncthreads();
  float m[20];
#pragma unroll
  for (int qq = 0; qq < 20; ++qq) m[qq] = 0.f;
  float c0 = fuse_b[o];
  for (int j = 0; j < 128; ++j) {
    float w = fuse_w[o * 129 + j];
#pragma unroll
    for (int qq = 0; qq < 20; ++qq) m[qq] += w * Ash[j][qq];
    c0 += w * Ash[j][20];
  }
#pragma unroll
  for (int qq = 0; qq < 20; ++qq) Mt[qq * 128 + o] = m[qq];
  C0[o] = c0;
  Wnt[o] = fuse_w[o * 129 + 128];
}

// ---- pack weight matrices [128][Kin] into bf16 B-fragment order ----
struct PackArgs {
  const float* src[7];
  u16* dst[7];
  int Kin[7];
  int ksCum[8];
};

__global__ void k_pack(PackArgs pa) {
  int bk = blockIdx.x;
  int mi = 0;
  while (bk >= pa.ksCum[mi + 1]) ++mi;
  int ks = bk - pa.ksCum[mi];
  const float* W = pa.src[mi];
  u16* D = pa.dst[mi] + ks * 4096;
  int Kin = pa.Kin[mi];
#pragma unroll
  for (int t = 0; t < 16; ++t) {
    int el = t * 256 + (int)threadIdx.x;
    int j = el & 7, ln = (el >> 3) & 63, ntile = el >> 9;
    int k = ks * 32 + ((ln >> 4) << 3) + j;
    int n = ntile * 16 + (ln & 15);
    float v = (k < Kin) ? W[n * Kin + k] : 0.0f;
    D[el] = f2bf(v);
  }
}

// ---- node encoder: h2[n] = M @ xflat[n] + C0 + Wnt*nt  (bf16 out) ----
__global__ __launch_bounds__(256) void k_encode(const float* __restrict__ x,
                                                const float* __restrict__ node_type,
                                                const float* __restrict__ Mt,
                                                const float* __restrict__ C0,
                                                const float* __restrict__ Wnt,
                                                u16* __restrict__ h2) {
  __shared__ float xs[2][20];
  int local = threadIdx.x >> 7, o = threadIdx.x & 127;
  int node = blockIdx.x * 2 + local;
  if (threadIdx.x < 40) {
    int nn = threadIdx.x / 20, qq = threadIdx.x % 20;
    xs[nn][qq] = x[(blockIdx.x * 2 + nn) * 20 + qq];
  }
  __syncthreads();
  float acc = C0[o] + Wnt[o] * node_type[node];
#pragma unroll
  for (int qq = 0; qq < 20; ++qq) acc += xs[local][qq] * Mt[qq * 128 + o];
  h2[node * HID + o] = f2bf(acc);
}

// ---- gnn1: per 64-edge tile: ea1 = g1e MLP(h2[row],h2[col],eattr); h3 = g1n MLP(h2[row],ea1)
__global__ __launch_bounds__(256, 2) void k_gnn1(
    const int* __restrict__ eidx, const float* __restrict__ eattr,
    const u16* __restrict__ h2, const u16* __restrict__ pW1, const u16* __restrict__ pW2,
    const u16* __restrict__ pW3, const u16* __restrict__ pW4, const float* __restrict__ b1,
    const float* __restrict__ b2, const float* __restrict__ b3, const float* __restrict__ b4,
    u16* __restrict__ ea1, u16* __restrict__ h3) {
  constexpr int S1 = 296, S2 = 136, IN2A = 64 * 296;
  __shared__ __align__(16) u16 lds[64 * 296 + 64 * 136];
  const int tid = threadIdx.x, lane = tid & 63, wave = tid >> 6;
  const int e0 = blockIdx.x * 64;
  const int* rowI = eidx;
  const int* colI = eidx + N_EDGES;

  // stage In1: cols 0..127 h2[row], 128..255 h2[col], 256..259 ea, 260..287 zero
#pragma unroll
  for (int it = 0; it < 8; ++it) {
    int task = tid + it * 256;
    int e = task >> 5, c = task & 31, ch = c & 15;
    int id = (c < 16) ? rowI[e0 + e] : colI[e0 + e];
    uint4 v = *(const uint4*)(h2 + id * HID + ch * 8);
    *(uint4*)(&lds[e * S1 + (c < 16 ? 0 : 128) + ch * 8]) = v;
  }
  {
    int e = tid >> 2, c = tid & 3;
    uint4 v; v.x = v.y = v.z = v.w = 0u;
    if (c == 0) {
      float4 a = *(const float4*)(eattr + (e0 + e) * 4);
      v.x = (unsigned)f2bf(a.x) | ((unsigned)f2bf(a.y) << 16);
      v.y = (unsigned)f2bf(a.z) | ((unsigned)f2bf(a.w) << 16);
    }
    *(uint4*)(&lds[e * S1 + 256 + c * 8]) = v;
  }
  __syncthreads();

  const int cn = lane & 15;
  float bb1_0 = b1[wave * 32 + cn], bb1_1 = b1[wave * 32 + 16 + cn];
  float bb2_0 = b2[wave * 32 + cn], bb2_1 = b2[wave * 32 + 16 + cn];

  f32x4 acc[4][2];
  zero_acc(acc);
  mfma_block<9, S1>(lds, pW1, lane, wave, acc);      // K=288 (260 padded)
  store_lds<true>(lds + IN2A, S2, acc, lane, wave, bb1_0, bb1_1);
  __syncthreads();

  zero_acc(acc);
  mfma_block<4, S2>(lds + IN2A, pW2, lane, wave, acc);  // K=128
  store_lds<false>(lds + 128, S1, acc, lane, wave, bb2_0, bb2_1);  // ea1 -> In1 cols 128..255
  __syncthreads();

  // flush ea1
#pragma unroll
  for (int it = 0; it < 4; ++it) {
    int cid = tid + it * 256, e = cid >> 4, c = cid & 15;
    uint4 v = *(const uint4*)(&lds[e * S1 + 128 + c * 8]);
    *(uint4*)(ea1 + (e0 + e) * HID + c * 8) = v;
  }

  if (e0 < N_NODES) {  // h3 only ever gathered at indices < N
    float bb3_0 = b3[wave * 32 + cn], bb3_1 = b3[wave * 32 + 16 + cn];
    float bb4_0 = b4[wave * 32 + cn], bb4_1 = b4[wave * 32 + 16 + cn];
    zero_acc(acc);
    mfma_block<8, S1>(lds, pW3, lane, wave, acc);  // K=256: [h2row | ea1]
    store_lds<true>(lds + IN2A, S2, acc, lane, wave, bb3_0, bb3_1);
    __syncthreads();
    zero_acc(acc);
    mfma_block<4, S2>(lds + IN2A, pW4, lane, wave, acc);
    store_lds<false>(lds, S1, acc, lane, wave, bb4_0, bb4_1);  // h3 -> In1 cols 0..127
    __syncthreads();
#pragma unroll
    for (int it = 0; it < 4; ++it) {
      int cid = tid + it * 256, e = cid >> 4, c = cid & 15;
      uint4 v = *(const uint4*)(&lds[e * S1 + c * 8]);
      *(uint4*)(h3 + (e0 + e) * HID + c * 8) = v;
    }
  }
}

// ---- gnn2 + fm1 + BN-stats: ea2 = g2e MLP(h3[row],h3[col],ea1); z = fm1(ea2); stats(z)
__global__ __launch_bounds__(256, 2) void k_gnn2(
    const int* __restrict__ eidx, const u16* __restrict__ h3, u16* ea1z,
    const u16* __restrict__ pW5, const u16* __restrict__ pW6, const u16* __restrict__ pW7,
    const float* __restrict__ b5, const float* __restrict__ b6, const float* __restrict__ b7,
    float* __restrict__ partials) {
  constexpr int S5 = 392, S2 = 136, IN6 = 64 * 392;
  __shared__ __align__(16) u16 lds[64 * 392 + 64 * 136];
  const int tid = threadIdx.x, lane = tid & 63, wave = tid >> 6;
  const int e0 = blockIdx.x * 64;
  const int* rowI = eidx;
  const int* colI = eidx + N_EDGES;

#pragma unroll
  for (int it = 0; it < 8; ++it) {
    int task = tid + it * 256;
    int e = task >> 5, c = task & 31, ch = c & 15;
    int id = (c < 16) ? rowI[e0 + e] : colI[e0 + e];
    uint4 v = *(const uint4*)(h3 + id * HID + ch * 8);
    *(uint4*)(&lds[e * S5 + (c < 16 ? 0 : 128) + ch * 8]) = v;
  }
#pragma unroll
  for (int it = 0; it < 4; ++it) {
    int cid = tid + it * 256, e = cid >> 4, c = cid & 15;
    uint4 v = *(const uint4*)(ea1z + (e0 + e) * HID + c * 8);
    *(uint4*)(&lds[e * S5 + 256 + c * 8]) = v;
  }
  __syncthreads();

  const int cn = lane & 15;
  float bb5_0 = b5[wave * 32 + cn], bb5_1 = b5[wave * 32 + 16 + cn];
  float bb6_0 = b6[wave * 32 + cn], bb6_1 = b6[wave * 32 + 16 + cn];
  float bb7_0 = b7[wave * 32 + cn], bb7_1 = b7[wave * 32 + 16 + cn];

  f32x4 acc[4][2];
  zero_acc(acc);
  mfma_block<12, S5>(lds, pW5, lane, wave, acc);  // K=384
  store_lds<true>(lds + IN6, S2, acc, lane, wave, bb5_0, bb5_1);
  __syncthreads();
  zero_acc(acc);
  mfma_block<4, S2>(lds + IN6, pW6, lane, wave, acc);
  store_lds<false>(lds, S5, acc, lane, wave, bb6_0, bb6_1);  // ea2 -> In5 cols 0..127
  __syncthreads();
  zero_acc(acc);
  mfma_block<4, S5>(lds, pW7, lane, wave, acc);  // z = fm1 @ ea2

  const int q = lane >> 4;
  float s0 = 0.f, q0 = 0.f, s1 = 0.f, q1 = 0.f;
#pragma unroll
  for (int mt = 0; mt < 4; ++mt)
#pragma unroll
    for (int r = 0; r < 4; ++r) {
      float v0 = acc[mt][0][r] + bb7_0;
      float v1 = acc[mt][1][r] + bb7_1;
      s0 += v0; q0 += v0 * v0;
      s1 += v1; q1 += v1 * v1;
      int row = mt * 16 + q * 4 + r;
      lds[row * S5 + 128 + wave * 32 + cn] = f2bf(v0);
      lds[row * S5 + 128 + wave * 32 + 16 + cn] = f2bf(v1);
    }
  s0 += __shfl_xor(s0, 16); s0 += __shfl_xor(s0, 32);
  q0 += __shfl_xor(q0, 16); q0 += __shfl_xor(q0, 32);
  s1 += __shfl_xor(s1, 16); s1 += __shfl_xor(s1, 32);
  q1 += __shfl_xor(q1, 16); q1 += __shfl_xor(q1, 32);
  if (lane < 16) {
    int base = blockIdx.x * 256;
    partials[base + wave * 32 + lane] = s0;
    partials[base + wave * 32 + 16 + lane] = s1;
    partials[base + 128 + wave * 32 + lane] = q0;
    partials[base + 128 + wave * 32 + 16 + lane] = q1;
  }
  __syncthreads();
#pragma unroll
  for (int it = 0; it < 4; ++it) {
    int cid = tid + it * 256, e = cid >> 4, c = cid & 15;
    uint4 v = *(const uint4*)(&lds[e * S5 + 128 + c * 8]);
    *(uint4*)(ea1z + (e0 + e) * HID + c * 8) = v;  // z overwrites ea1 (same rows, safe)
  }
}

__global__ void k_reduce(const float* __restrict__ partials, float* __restrict__ bnacc) {
  int t = threadIdx.x;  // 256
  float s = 0.f;
  for (int b = blockIdx.x; b < 3125; b += 64) s += partials[b * 256 + t];
  atomicAdd(&bnacc[t], s);
}

__global__ void k_bnfin(const float* __restrict__ bnacc, const float* __restrict__ bn_g,
                        const float* __restrict__ bn_b, float* __restrict__ ss) {
  int t = threadIdx.x;  // 128
  float inv = 1.0f / (float)N_EDGES;
  float mu = bnacc[t] * inv;
  float var = bnacc[128 + t] * inv - mu * mu;
  float sc = bn_g[t] * rsqrtf(var + 1e-5f);
  ss[t] = sc;
  ss[128 + t] = bn_b[t] - mu * sc;
}

// ---- head: out = fm_w2 @ relu(BN(z)) + fm_b2, one edge per wave iteration ----
__global__ __launch_bounds__(256) void k_head(const u16* __restrict__ z,
                                              const float* __restrict__ ss,
                                              const float* __restrict__ w2,
                                              const float* __restrict__ b2,
                                              float* __restrict__ out) {
  const int lane = threadIdx.x & 63;
  const int wv = (int)(blockIdx.x * blockDim.x + threadIdx.x) >> 6;
  const int nwv = (int)(gridDim.x * blockDim.x) >> 6;
  const int c0 = lane * 2, c1 = c0 + 1;
  float s0 = ss[c0], s1 = ss[c1], h0 = ss[128 + c0], h1 = ss[128 + c1];
  float w00 = w2[c0], w01 = w2[c1], w10 = w2[128 + c0], w11 = w2[128 + c1];
  float w20 = w2[256 + c0], w21 = w2[256 + c1];
  float bb0 = b2[0], bb1 = b2[1], bb2 = b2[2];
  for (int e = wv; e < N_EDGES; e += nwv) {
    unsigned zz = *(const unsigned*)(z + e * HID + c0);
    float r0 = fmaxf(bf2f(zz & 0xffffu) * s0 + h0, 0.f);
    float r1 = fmaxf(bf2f(zz >> 16) * s1 + h1, 0.f);
    float p0 = r0 * w00 + r1 * w01;
    float p1 = r0 * w10 + r1 * w11;
    float p2 = r0 * w20 + r1 * w21;
#pragma unroll
    for (int off = 32; off > 0; off >>= 1) {
      p0 += __shfl_xor(p0, off);
      p1 += __shfl_xor(p1, off);
      p2 += __shfl_xor(p2, off);
    }
    if (lane == 0) {
      out[e * 3 + 0] = p0 + bb0;
      out[e * 3 + 1] = p1 + bb1;
      out[e * 3 + 2] = p2 + bb2;
    }
  }
}

extern "C" void kernel_launch(void* const* d_in, const int* in_sizes, int n_in,
                              void* d_out, int out_size, void* d_ws, size_t ws_size,
                              hipStream_t stream) {
  const float* x         = (const float*)d_in[0];
  const int* eidx        = (const int*)d_in[1];
  const float* eattr     = (const float*)d_in[2];
  const float* node_type = (const float*)d_in[4];
  const float* emb       = (const float*)d_in[5];
  const float* conv_w    = (const float*)d_in[6];
  const float* conv_b    = (const float*)d_in[7];
  const float* fuse_w    = (const float*)d_in[8];
  const float* fuse_b    = (const float*)d_in[9];
  const float* g1e_w1    = (const float*)d_in[10];
  const float* g1e_b1    = (const float*)d_in[11];
  const float* g1e_w2    = (const float*)d_in[12];
  const float* g1e_b2    = (const float*)d_in[13];
  const float* g1n_w1    = (const float*)d_in[14];
  const float* g1n_b1    = (const float*)d_in[15];
  const float* g1n_w2    = (const float*)d_in[16];
  const float* g1n_b2    = (const float*)d_in[17];
  const float* g2e_w1    = (const float*)d_in[18];
  const float* g2e_b1    = (const float*)d_in[19];
  const float* g2e_w2    = (const float*)d_in[20];
  const float* g2e_b2    = (const float*)d_in[21];
  // d_in[22..25] = g2n_* : dead code in the reference (output unused)
  const float* fm_w1     = (const float*)d_in[26];
  const float* fm_b1     = (const float*)d_in[27];
  const float* bn_g      = (const float*)d_in[28];
  const float* bn_b      = (const float*)d_in[29];
  const float* fm_w2     = (const float*)d_in[30];
  const float* fm_b2     = (const float*)d_in[31];
  float* out = (float*)d_out;

  char* ws = (char*)d_ws;
  size_t off = 0;
  auto take = [&](size_t bytes) {
    void* p = ws + off;
    off = (off + bytes + 255) & ~(size_t)255;
    return p;
  };
  u16* h2   = (u16*)take((size_t)N_NODES * HID * 2);
  u16* h3   = (u16*)take((size_t)20032 * HID * 2);  // only rows < N ever gathered
  u16* ea1z = (u16*)take((size_t)N_EDGES * HID * 2);
  float* Mt    = (float*)take(20 * 128 * 4);
  float* C0    = (float*)take(128 * 4);
  float* Wnt   = (float*)take(128 * 4);
  float* bnacc = (float*)take(256 * 4);
  float* bnss  = (float*)take(256 * 4);
  float* partials = (float*)take((size_t)3125 * 256 * 4);
  u16* pW1 = (u16*)take(9 * 4096 * 2);
  u16* pW2 = (u16*)take(4 * 4096 * 2);
  u16* pW3 = (u16*)take(8 * 4096 * 2);
  u16* pW4 = (u16*)take(4 * 4096 * 2);
  u16* pW5 = (u16*)take(12 * 4096 * 2);
  u16* pW6 = (u16*)take(4 * 4096 * 2);
  u16* pW7 = (u16*)take(4 * 4096 * 2);

  hipMemsetAsync(bnacc, 0, 256 * 4, stream);
  k_fold<<<1, 128, 0, stream>>>(emb, conv_w, conv_b, fuse_w, fuse_b, Mt, C0, Wnt);

  PackArgs pa;
  const float* srcs[7] = {g1e_w1, g1e_w2, g1n_w1, g1n_w2, g2e_w1, g2e_w2, fm_w1};
  u16* dsts[7] = {pW1, pW2, pW3, pW4, pW5, pW6, pW7};
  int kins[7] = {260, 128, 256, 128, 384, 128, 128};
  int kst[7] = {9, 4, 8, 4, 12, 4, 4};
  int cum = 0;
  for (int i = 0; i < 7; ++i) {
    pa.src[i] = srcs[i]; pa.dst[i] = dsts[i]; pa.Kin[i] = kins[i];
    pa.ksCum[i] = cum; cum += kst[i];
  }
  pa.ksCum[7] = cum;  // 45
  k_pack<<<45, 256, 0, stream>>>(pa);

  k_encode<<<N_NODES / 2, 256, 0, stream>>>(x, node_type, Mt, C0, Wnt, h2);
  k_gnn1<<<N_EDGES / 64, 256, 0, stream>>>(eidx, eattr, h2, pW1, pW2, pW3, pW4,
                                           g1e_b1, g1e_b2, g1n_b1, g1n_b2, ea1z, h3);
  k_gnn2<<<N_EDGES / 64, 256, 0, stream>>>(eidx, h3, ea1z, pW5, pW6, pW7,
                                           g2e_b1, g2e_b2, fm_b1, partials);
  k_reduce<<<64, 256, 0, stream>>>(partials, bnacc);
  k_bnfin<<<1, 128, 0, stream>>>(bnacc, bn_g, bn_b, bnss);
  k_head<<<512, 256, 0, stream>>>(ea1z, bnss, fm_w2, fm_b2, out);
}